// Round 11
// baseline (335.690 us; speedup 1.0000x reference)
//
#include <hip/hip_runtime.h>
#include <math.h>

// GCN 2-layer: N=100K nodes, E=3.2M edges (+N self loops), 64 -> 128 -> 64.
//  - Fold norm: out[d] = dinv[d] * sum_s (dinv[s]*h[s]) + b
//  - R10 profile: k_finalize top dispatch (60us, occupancy 7%, VALU 3.5%) —
//    196 blocks < 256 CUs, pure latency serialization. R11: BSHIFT 9->7
//    (128-node buckets, nb=782, ~3 blocks/CU, 1/4 per-block work); scans
//    widened to 4 elems/thread; ebuf packs dl:7|src:23. agg/mlp untouched.

#define IN_C 64
#define HID_C 128
#define OUT_C 64
#define BSHIFT 7
#define BW (1 << BSHIFT)          // 128 nodes per bucket
#define NPB 512                   // partition blocks
#define NBMAX 1024                // max buckets supported by 4-elem scans

typedef __attribute__((ext_vector_type(8))) short bf16x8;
typedef __attribute__((ext_vector_type(4))) float f32x4;
typedef __attribute__((ext_vector_type(2))) float v2f;

__device__ __forceinline__ unsigned short f2bf(float f) {
  unsigned u = __float_as_uint(f);
  return (unsigned short)((u + 0x7FFF + ((u >> 16) & 1)) >> 16);  // RNE
}
__device__ __forceinline__ v2f cvt2(unsigned u) {
  v2f r;
  r.x = __uint_as_float(u << 16);          // low bf16 -> f32
  r.y = __uint_as_float(u & 0xFFFF0000u);  // high bf16 -> f32
  return r;
}
__device__ __forceinline__ unsigned pack2(v2f v) {
  return ((unsigned)f2bf(v.y) << 16) | f2bf(v.x);
}

// ---- pass 1: detect + per-block bucket histogram + (extras: wconv, zero rows)

__global__ __launch_bounds__(256) void k_part1(const int* __restrict__ ei, int e, int n,
    int nb, int* __restrict__ pcnt,
    const float* __restrict__ W1, const float* __restrict__ W2,
    unsigned short* __restrict__ Wt1, unsigned short* __restrict__ Wt2,
    unsigned short* __restrict__ xs_zero, unsigned short* __restrict__ h2s_zero) {
  extern __shared__ int lh[];
  const int t = threadIdx.x;
  if (blockIdx.x >= NPB) {                 // extra blocks: weights + zero rows
    int bb = blockIdx.x - NPB;
    if (bb == 32) {
      if (t < 64) { xs_zero[t] = 0; h2s_zero[t] = 0; }
      return;
    }
    int i = bb * 256 + t;
    if (i < IN_C * HID_C) {
      int k = i >> 7, c = i & (HID_C - 1);
      Wt1[c * IN_C + k] = f2bf(W1[i]);
    }
    if (i < HID_C * OUT_C) {
      int k = i >> 6, c = i & (OUT_C - 1);
      Wt2[c * HID_C + k] = f2bf(W2[i]);
    }
    return;
  }
  __shared__ int sflag;
  if (t == 0) sflag = 0;
  for (int i = t; i < nb; i += 256) lh[i] = 0;
  __syncthreads();
  const int chunk = (e + NPB - 1) / NPB;
  const int lo = blockIdx.x * chunk;
  const int hi = min(lo + chunk, e);
  {  // per-chunk int32/int64 detect: odd words of int64 values (<2^31) are 0
    int lim = min(hi, lo + 512);
    int f = 0;
    for (int i = lo + t; i < lim; i += 256)
      if (ei[2 * i + 1] != 0) f = 1;
    if (f) sflag = 1;
  }
  __syncthreads();
  const int f = sflag;                     // 1 => int32 layout
  for (int i = lo + t; i < hi; i += 256) {
    int d;
    if (f) d = __builtin_nontemporal_load(&ei[e + i]);
    else   d = (int)__builtin_nontemporal_load(&((const long long*)ei)[e + i]);
    d = min(max(d, 0), n - 1);
    atomicAdd(&lh[d >> BSHIFT], 1);
  }
  __syncthreads();
  for (int i = t; i < nb; i += 256) pcnt[(size_t)i * NPB + blockIdx.x] = lh[i];
}

// ---- per-bucket parallel scan over NPB block-counts ------------------------

__global__ __launch_bounds__(256) void k_bscan(int* __restrict__ pcnt,
    int* __restrict__ btot) {
  __shared__ int ws[256];
  const int b = blockIdx.x;
  const int t = threadIdx.x;
  int* row = pcnt + (size_t)b * NPB;
  int2 v = ((int2*)row)[t];                // NPB = 512 = 256 x 2
  int s0 = v.x;
  int s1 = s0 + v.y;
  ws[t] = s1;
  __syncthreads();
  for (int off = 1; off < 256; off <<= 1) {
    int u = (t >= off) ? ws[t - off] : 0;
    __syncthreads();
    ws[t] += u;
    __syncthreads();
  }
  int base = (t == 0) ? 0 : ws[t - 1];
  ((int2*)row)[t] = make_int2(base, base + s0);
  if (t == 255) btot[b] = ws[255];
}

// ---- pass 2: direct partitioned scatter, u32-packed (dl:7 | src:23) --------

__global__ __launch_bounds__(256) void k_part2(const int* __restrict__ ei, int e, int n,
    int nb, const int* __restrict__ pcnt, const int* __restrict__ btot,
    unsigned* __restrict__ ebuf) {
  __shared__ int ws[256];
  __shared__ int base_l[NBMAX];
  __shared__ int cur[NBMAX];
  __shared__ int sflag;
  const int t = threadIdx.x;
  if (t == 0) sflag = 0;
  // 4-elem/thread exclusive scan of btot -> base_l
  const int b4 = t * 4;
  int v0 = (b4 + 0 < nb) ? btot[b4 + 0] : 0;
  int v1 = (b4 + 1 < nb) ? btot[b4 + 1] : 0;
  int v2 = (b4 + 2 < nb) ? btot[b4 + 2] : 0;
  int v3 = (b4 + 3 < nb) ? btot[b4 + 3] : 0;
  int p0 = v0, p1 = p0 + v1, p2 = p1 + v2, p3 = p2 + v3;
  ws[t] = p3;
  __syncthreads();
  for (int off = 1; off < 256; off <<= 1) {
    int u = (t >= off) ? ws[t - off] : 0;
    __syncthreads();
    ws[t] += u;
    __syncthreads();
  }
  {
    int base = (t == 0) ? 0 : ws[t - 1];
    const int blk = blockIdx.x;
    if (b4 + 0 < nb) { base_l[b4 + 0] = base      + pcnt[(size_t)(b4 + 0) * NPB + blk]; cur[b4 + 0] = 0; }
    if (b4 + 1 < nb) { base_l[b4 + 1] = base + p0 + pcnt[(size_t)(b4 + 1) * NPB + blk]; cur[b4 + 1] = 0; }
    if (b4 + 2 < nb) { base_l[b4 + 2] = base + p1 + pcnt[(size_t)(b4 + 2) * NPB + blk]; cur[b4 + 2] = 0; }
    if (b4 + 3 < nb) { base_l[b4 + 3] = base + p2 + pcnt[(size_t)(b4 + 3) * NPB + blk]; cur[b4 + 3] = 0; }
  }
  const int chunk = (e + NPB - 1) / NPB;
  const int lo = blockIdx.x * chunk;
  const int hi = min(lo + chunk, e);
  {
    int lim = min(hi, lo + 512);
    int f = 0;
    for (int i = lo + t; i < lim; i += 256)
      if (ei[2 * i + 1] != 0) f = 1;
    if (f) sflag = 1;
  }
  __syncthreads();
  const int f = sflag;
  for (int i = lo + t; i < hi; i += 256) {
    int s, d;
    if (f) {
      s = __builtin_nontemporal_load(&ei[i]);
      d = __builtin_nontemporal_load(&ei[e + i]);
    } else {
      s = (int)__builtin_nontemporal_load(&((const long long*)ei)[i]);
      d = (int)__builtin_nontemporal_load(&((const long long*)ei)[e + i]);
    }
    s = min(max(s, 0), n - 1);
    d = min(max(d, 0), n - 1);
    int b = d >> BSHIFT;
    int slot = atomicAdd(&cur[b], 1);
    ebuf[base_l[b] + slot] = ((unsigned)(d & (BW - 1)) << 23) | (unsigned)s;
  }
}

// ---- per-bucket finalize: degree, scan, row_ptr, dinv, col scatter, xs -----

__global__ __launch_bounds__(256) void k_finalize(const unsigned* __restrict__ ebuf,
    const int* __restrict__ btot, const float* __restrict__ x,
    unsigned short* __restrict__ xs, int n, int nb,
    int* __restrict__ row_ptr, float* __restrict__ dinv, int* __restrict__ col) {
  __shared__ int ws[256];
  __shared__ int sE[NBMAX];
  __shared__ int sC[NBMAX];
  __shared__ int ldeg[BW];
  __shared__ int lcur[BW];
  __shared__ float sdv[BW];
  const int b = blockIdx.x;
  const int t = threadIdx.x;
  // 4-elem/thread dual inclusive scan of btot -> sE (edges), sC (edges+nodes)
  {
    const int b4 = t * 4;
    int e0 = 0, e1 = 0, e2 = 0, e3 = 0, c0 = 0, c1 = 0, c2 = 0, c3 = 0;
    if (b4 + 0 < nb) { e0 = btot[b4 + 0]; c0 = e0 + min(BW, n - (b4 + 0) * BW); }
    if (b4 + 1 < nb) { e1 = btot[b4 + 1]; c1 = e1 + min(BW, n - (b4 + 1) * BW); }
    if (b4 + 2 < nb) { e2 = btot[b4 + 2]; c2 = e2 + min(BW, n - (b4 + 2) * BW); }
    if (b4 + 3 < nb) { e3 = btot[b4 + 3]; c3 = e3 + min(BW, n - (b4 + 3) * BW); }
    int pe0 = e0, pe1 = pe0 + e1, pe2 = pe1 + e2, pe3 = pe2 + e3;
    int pc0 = c0, pc1 = pc0 + c1, pc2 = pc1 + c2, pc3 = pc2 + c3;
    // pack both 16-bit-safe? totals can exceed 2^16 — do two ladder passes via
    // a single ladder on packed int2 stored as two LDS arrays: reuse ws twice.
    ws[t] = pe3;
    __syncthreads();
    for (int off = 1; off < 256; off <<= 1) {
      int u = (t >= off) ? ws[t - off] : 0;
      __syncthreads();
      ws[t] += u;
      __syncthreads();
    }
    int baseE = (t == 0) ? 0 : ws[t - 1];
    if (b4 + 0 < nb) sE[b4 + 0] = baseE + pe0;
    if (b4 + 1 < nb) sE[b4 + 1] = baseE + pe1;
    if (b4 + 2 < nb) sE[b4 + 2] = baseE + pe2;
    if (b4 + 3 < nb) sE[b4 + 3] = baseE + pe3;
    __syncthreads();
    ws[t] = pc3;
    __syncthreads();
    for (int off = 1; off < 256; off <<= 1) {
      int u = (t >= off) ? ws[t - off] : 0;
      __syncthreads();
      ws[t] += u;
      __syncthreads();
    }
    int baseC = (t == 0) ? 0 : ws[t - 1];
    if (b4 + 0 < nb) sC[b4 + 0] = baseC + pc0;
    if (b4 + 1 < nb) sC[b4 + 1] = baseC + pc1;
    if (b4 + 2 < nb) sC[b4 + 2] = baseC + pc2;
    if (b4 + 3 < nb) sC[b4 + 3] = baseC + pc3;
    __syncthreads();
  }
  const int eb = (b == 0) ? 0 : sE[b - 1];
  const int ee = sE[b];
  const int cb = (b == 0) ? 0 : sC[b - 1];
  const int lo = b * BW;
  const int nn = min(BW, n - lo);
  if (t < BW) ldeg[t] = (t < nn) ? 1 : 0;   // self-loop
  __syncthreads();
  for (int j = eb + t; j < ee; j += 256) {
    int dl = (int)(ebuf[j] >> 23);
    atomicAdd(&ldeg[dl], 1);
  }
  __syncthreads();
  // 128-wide scan of ldeg via 256-ladder (upper lanes carry 0)
  int dg = (t < BW) ? ldeg[t] : 0;
  ws[t] = dg;
  __syncthreads();
  for (int off = 1; off < 256; off <<= 1) {
    int u = (t >= off) ? ws[t - off] : 0;
    __syncthreads();
    ws[t] += u;
    __syncthreads();
  }
  int excl = ws[t] - dg;
  if (t < nn) {
    int base = cb + excl;
    float dv = rsqrtf((float)dg);
    row_ptr[lo + t] = base;
    dinv[lo + t] = dv;
    sdv[t] = dv;
    col[base] = lo + t;          // self-loop entry
    lcur[t] = excl + 1;
  }
  if (b == nb - 1 && t == 0) row_ptr[n] = sC[nb - 1];
  __syncthreads();
  for (int j = eb + t; j < ee; j += 256) {
    unsigned pk = ebuf[j];
    int s = (int)(pk & 0x7FFFFF);
    int dl = (int)(pk >> 23);
    int p = atomicAdd(&lcur[dl], 1);
    col[cb + p] = s;
  }
  // fused k_scale: xs[row] = bf16(x[row] * dinv[row]) for this bucket's rows
  const float4* x4 = (const float4*)x;
  for (int idx = t; idx < nn * 16; idx += 256) {
    int row = idx >> 4, q = idx & 15;
    float sc2 = sdv[row];
    float4 v = x4[(size_t)(lo + row) * 16 + q];
    ushort4 o;
    o.x = f2bf(v.x * sc2); o.y = f2bf(v.y * sc2);
    o.z = f2bf(v.z * sc2); o.w = f2bf(v.w * sc2);
    ((ushort4*)xs)[(size_t)(lo + row) * 16 + q] = o;
  }
}

// ---- aggregation: 8 lanes/edge x 16B, 8 slots, depth-4, pk_add converts ----
// feat must have a zero row at index n.

template<bool BIAS, bool OUT_BF16>
__global__ __launch_bounds__(256) void k_agg(const unsigned short* __restrict__ feat,
    const int* __restrict__ row_ptr, const int* __restrict__ col,
    const float* __restrict__ dinv, const float* __restrict__ bias,
    void* __restrict__ outv, int n) {
  const int wid = threadIdx.x >> 6;
  const int lane = threadIdx.x & 63;
  const int es = lane >> 3;      // edge slot 0..7
  const int c8 = lane & 7;       // 16B channel chunk (8 ch)
  const int d = blockIdx.x * 4 + wid;
  if (d >= n) return;
  const int beg = row_ptr[d], end = row_ptr[d + 1];
  const uint4* f16 = (const uint4*)feat;   // row stride = 8 chunks
  const int rem = end - beg - es;
  const int c = (rem > 0) ? ((rem + 7) >> 3) : 0;
  const int last = end - 1;
  v2f a0 = {0.f, 0.f}, a1 = {0.f, 0.f}, a2 = {0.f, 0.f}, a3 = {0.f, 0.f};
  for (int g = 0; g < c; g += 4) {
    int j0 = beg + es + 8 * g;
    int i0 = col[j0];
    int i1 = col[min(j0 + 8, last)];
    int i2 = col[min(j0 + 16, last)];
    int i3 = col[min(j0 + 24, last)];
    if (g + 1 >= c) i1 = n;
    if (g + 2 >= c) i2 = n;
    if (g + 3 >= c) i3 = n;
    uint4 u0 = f16[(size_t)i0 * 8 + c8];
    uint4 u1 = f16[(size_t)i1 * 8 + c8];
    uint4 u2 = f16[(size_t)i2 * 8 + c8];
    uint4 u3 = f16[(size_t)i3 * 8 + c8];
    a0 += cvt2(u0.x) + cvt2(u1.x) + cvt2(u2.x) + cvt2(u3.x);
    a1 += cvt2(u0.y) + cvt2(u1.y) + cvt2(u2.y) + cvt2(u3.y);
    a2 += cvt2(u0.z) + cvt2(u1.z) + cvt2(u2.z) + cvt2(u3.z);
    a3 += cvt2(u0.w) + cvt2(u1.w) + cvt2(u2.w) + cvt2(u3.w);
  }
#pragma unroll
  for (int off = 8; off <= 32; off <<= 1) {
    v2f o0, o1, o2, o3;
    o0.x = __shfl_xor(a0.x, off); o0.y = __shfl_xor(a0.y, off);
    o1.x = __shfl_xor(a1.x, off); o1.y = __shfl_xor(a1.y, off);
    o2.x = __shfl_xor(a2.x, off); o2.y = __shfl_xor(a2.y, off);
    o3.x = __shfl_xor(a3.x, off); o3.y = __shfl_xor(a3.y, off);
    a0 += o0; a1 += o1; a2 += o2; a3 += o3;
  }
  if (es == 0) {
    float sc = dinv[d];
    v2f vs = {sc, sc};
    a0 *= vs; a1 *= vs; a2 *= vs; a3 *= vs;
    if (BIAS) {
      const v2f* b2v = (const v2f*)bias;
      a0 += b2v[c8 * 4 + 0]; a1 += b2v[c8 * 4 + 1];
      a2 += b2v[c8 * 4 + 2]; a3 += b2v[c8 * 4 + 3];
    }
    if (OUT_BF16) {
      uint4 o;
      o.x = pack2(a0); o.y = pack2(a1); o.z = pack2(a2); o.w = pack2(a3);
      ((uint4*)outv)[(size_t)d * 8 + c8] = o;
    } else {
      float4* o4 = (float4*)outv;
      o4[(size_t)d * 16 + c8 * 2]     = make_float4(a0.x, a0.y, a1.x, a1.y);
      o4[(size_t)d * 16 + c8 * 2 + 1] = make_float4(a2.x, a2.y, a3.x, a3.y);
    }
  }
}

// ---- fused MLP: h2s = (relu(A1 @ Wt1^T + b1) * dinv) @ Wt2^T, all bf16 -----
// block = 16 rows, 4 waves; gemm1 tile staged in LDS (pad 136 -> 2-way free)

__global__ __launch_bounds__(256) void k_mlp(const unsigned short* __restrict__ A1,
    const unsigned short* __restrict__ Wt1, const unsigned short* __restrict__ Wt2,
    const float* __restrict__ b1, const float* __restrict__ dinv,
    unsigned short* __restrict__ h2s, int M) {
  __shared__ unsigned short sA[16 * 136];
  const int wv = threadIdx.x >> 6;
  const int lane = threadIdx.x & 63;
  const int m = lane & 15;
  const int q = lane >> 4;
  const int r0 = blockIdx.x * 16;
  const int ra = min(r0 + m, M - 1);
  // GEMM1: C1[16][128]; wave wv covers col-tiles wv and wv+4
  f32x4 acc0 = {0.f, 0.f, 0.f, 0.f}, acc1 = {0.f, 0.f, 0.f, 0.f};
#pragma unroll
  for (int kt = 0; kt < IN_C; kt += 32) {
    bf16x8 a  = *(const bf16x8*)&A1[(size_t)ra * IN_C + kt + q * 8];
    bf16x8 p  = *(const bf16x8*)&Wt1[(size_t)(wv * 16 + m) * IN_C + kt + q * 8];
    bf16x8 p2 = *(const bf16x8*)&Wt1[(size_t)((wv + 4) * 16 + m) * IN_C + kt + q * 8];
    acc0 = __builtin_amdgcn_mfma_f32_16x16x32_bf16(a, p, acc0, 0, 0, 0);
    acc1 = __builtin_amdgcn_mfma_f32_16x16x32_bf16(a, p2, acc1, 0, 0, 0);
  }
  float dv[4];
#pragma unroll
  for (int i = 0; i < 4; i++) dv[i] = dinv[min(r0 + q * 4 + i, M - 1)];
  {
    int c = wv * 16 + m;
    float bv = b1[c];
#pragma unroll
    for (int i = 0; i < 4; i++)
      sA[(q * 4 + i) * 136 + c] = f2bf(fmaxf(acc0[i] + bv, 0.f) * dv[i]);
    c = (wv + 4) * 16 + m;
    bv = b1[c];
#pragma unroll
    for (int i = 0; i < 4; i++)
      sA[(q * 4 + i) * 136 + c] = f2bf(fmaxf(acc1[i] + bv, 0.f) * dv[i]);
  }
  __syncthreads();
  // GEMM2: C2[16][64]; wave wv covers cols wv*16..+15
  f32x4 acc = {0.f, 0.f, 0.f, 0.f};
#pragma unroll
  for (int kt = 0; kt < HID_C; kt += 32) {
    bf16x8 a = *(const bf16x8*)&sA[m * 136 + kt + q * 8];
    bf16x8 p = *(const bf16x8*)&Wt2[(size_t)(wv * 16 + m) * HID_C + kt + q * 8];
    acc = __builtin_amdgcn_mfma_f32_16x16x32_bf16(a, p, acc, 0, 0, 0);
  }
  int c = wv * 16 + m;
#pragma unroll
  for (int i = 0; i < 4; i++) {
    int row = r0 + q * 4 + i;
    if (row < M) h2s[(size_t)row * OUT_C + c] = f2bf(acc[i]);
  }
}

// ---- launch ---------------------------------------------------------------

extern "C" void kernel_launch(void* const* d_in, const int* in_sizes, int n_in,
                              void* d_out, int out_size, void* d_ws, size_t ws_size,
                              hipStream_t stream) {
  const float* x  = (const float*)d_in[0];
  const int*   ei = (const int*)d_in[1];
  const float* W1 = (const float*)d_in[2];
  const float* b1 = (const float*)d_in[3];
  const float* W2 = (const float*)d_in[4];
  const float* b2 = (const float*)d_in[5];
  float* out = (float*)d_out;

  const int n = in_sizes[0] / IN_C;   // 100000
  const int e = in_sizes[1] / 2;      // 3200000
  const int nb = (n + BW - 1) >> BSHIFT;  // 782 (must be <= NBMAX)

  char* p = (char*)d_ws;
  auto alloc = [&](size_t bytes) {
    char* r = p;
    p += (bytes + 255) & ~(size_t)255;
    return r;
  };
  int*   pcnt       = (int*)alloc((size_t)nb * NPB * 4);
  int*   btot       = (int*)alloc((size_t)nb * 4);
  int*   row_ptr    = (int*)alloc((size_t)(n + 1) * 4);
  float* dinv       = (float*)alloc((size_t)n * 4);
  int*   col        = (int*)alloc((size_t)(e + n) * 4);
  unsigned* ebuf    = (unsigned*)alloc((size_t)e * 4);
  unsigned short* xs  = (unsigned short*)alloc((size_t)(n + 1) * IN_C * 2);   // + zero row
  unsigned short* A1  = (unsigned short*)alloc((size_t)n * IN_C * 2);
  unsigned short* h2s = (unsigned short*)alloc((size_t)(n + 1) * OUT_C * 2);  // + zero row
  unsigned short* Wt1 = (unsigned short*)alloc((size_t)IN_C * HID_C * 2);
  unsigned short* Wt2 = (unsigned short*)alloc((size_t)HID_C * OUT_C * 2);

  // CSR build + weights + zero rows (part1 extras)
  k_part1<<<NPB + 33, 256, nb * 4, stream>>>(ei, e, n, nb, pcnt, W1, W2, Wt1, Wt2,
      xs + (size_t)n * IN_C, h2s + (size_t)n * OUT_C);
  k_bscan<<<nb, 256, 0, stream>>>(pcnt, btot);
  k_part2<<<NPB, 256, 0, stream>>>(ei, e, n, nb, pcnt, btot, ebuf);
  k_finalize<<<nb, 256, 0, stream>>>(ebuf, btot, x, xs, n, nb, row_ptr, dinv, col);

  // Layer 1 aggregate -> bf16 A1; fused MLP -> bf16 h2s; layer 2 aggregate
  k_agg<false, true><<<(n + 3) / 4, 256, 0, stream>>>(xs, row_ptr, col, dinv, nullptr, A1, n);
  k_mlp<<<(n + 15) / 16, 256, 0, stream>>>(A1, Wt1, Wt2, b1, dinv, h2s, n);
  k_agg<true, false><<<(n + 3) / 4, 256, 0, stream>>>(h2s, row_ptr, col, dinv, b2, out, n);
}